// Round 1
// baseline (428.849 us; speedup 1.0000x reference)
//
#include <hip/hip_runtime.h>

// out[n, k*D + d] = M[k, n, d]  with K=4, N=500000, D=128, fp32.
// Pure bandwidth-bound permutation. float4 vectorized, output-linear
// (write side perfectly coalesced; read side contiguous in 512B runs).

static constexpr int K = 4;
static constexpr int N = 500000;
static constexpr int D = 128;           // floats per (k,n) row
static constexpr long long TOTAL = (long long)K * N * D;   // 256,000,000 floats
static constexpr long long TOTAL4 = TOTAL / 4;             // 64,000,000 float4

__global__ void msgcat_kernel(const float4* __restrict__ in, float4* __restrict__ out) {
    const long long stride = (long long)gridDim.x * blockDim.x;
    for (long long i4 = (long long)blockIdx.x * blockDim.x + threadIdx.x;
         i4 < TOTAL4; i4 += stride) {
        // output flat float index
        const long long f = i4 << 2;
        const long long n   = f >> 9;          // / (K*D) == /512
        const int       rem = (int)(f & 511);  // % 512
        const int       k   = rem >> 7;        // /128
        const int       d   = rem & 127;       // %128
        // input flat float index: k*N*D + n*D + d  (d multiple of 4 -> aligned float4)
        const long long g = (long long)k * ((long long)N * D) + (n << 7) + d;
        out[i4] = in[g >> 2];
    }
}

extern "C" void kernel_launch(void* const* d_in, const int* in_sizes, int n_in,
                              void* d_out, int out_size, void* d_ws, size_t ws_size,
                              hipStream_t stream) {
    const float4* in  = (const float4*)d_in[0];
    float4*       out = (float4*)d_out;
    const int block = 256;
    // cap grid at 256 CU * 8 blocks/CU = 2048, grid-stride the rest
    long long want = (TOTAL4 + block - 1) / block;
    int grid = (int)(want < 2048 ? want : 2048);
    msgcat_kernel<<<grid, block, 0, stream>>>(in, out);
}

// Round 3
// 382.560 us; speedup vs baseline: 1.1210x; 1.1210x over previous
//
#include <hip/hip_runtime.h>

// out[n, k*D + d] = M[k, n, d]  with K=4, N=500000, D=128, fp32.
// Wave-per-row mapping: wave w owns output row n=w.
//   lane l, j in {0,1}:  k = (l>>5) + 2j, c = l&31   (c = float4 column)
//   read  in4[k*N*32 + n*32 + c]   -> 512B contiguous per 32-lane half
//   write out4[n*128 + 64j + l]    -> fully lane-consecutive (1KB/instr)
// Non-temporal loads/stores (native ext_vector_type so the builtin accepts it).

typedef float v4f __attribute__((ext_vector_type(4)));

static constexpr int  K = 4;
static constexpr long long N = 500000;
static constexpr int  D = 128;
static constexpr long long ROW4   = D / 4;          // 32 v4f per (k,n) row
static constexpr long long PLANE4 = N * ROW4;       // v4f per k-plane

__global__ void msgcat_kernel(const v4f* __restrict__ in, v4f* __restrict__ out) {
    const int lane        = threadIdx.x & 63;
    const int waveInBlock = threadIdx.x >> 6;
    const int wavesPerBlk = blockDim.x >> 6;
    const long long wavesInGrid = (long long)gridDim.x * wavesPerBlk;

    const int k0 = lane >> 5;        // 0 or 1
    const int c  = lane & 31;        // v4f column within 128-float row

    for (long long n = (long long)blockIdx.x * wavesPerBlk + waveInBlock;
         n < N; n += wavesInGrid) {
        const long long inBase  = n * ROW4 + c;
        const long long outBase = n * (4 * ROW4) + lane;
        v4f a = __builtin_nontemporal_load(&in[(long long)k0       * PLANE4 + inBase]);
        v4f b = __builtin_nontemporal_load(&in[(long long)(k0 + 2) * PLANE4 + inBase]);
        __builtin_nontemporal_store(a, &out[outBase]);
        __builtin_nontemporal_store(b, &out[outBase + 64]);
    }
}

extern "C" void kernel_launch(void* const* d_in, const int* in_sizes, int n_in,
                              void* d_out, int out_size, void* d_ws, size_t ws_size,
                              hipStream_t stream) {
    const v4f* in  = (const v4f*)d_in[0];
    v4f*       out = (v4f*)d_out;
    const int block = 256;                 // 4 waves/block
    const int grid  = 2048;                // 8 blocks/CU on 256 CUs; grid-stride over n
    msgcat_kernel<<<grid, block, 0, stream>>>(in, out);
}